// Round 5
// baseline (94.028 us; speedup 1.0000x reference)
//
#include <hip/hip_runtime.h>
#include <math.h>

#define NCLS 21
#define DD   256
#define HWPIX (512*512)          // 262144 pixels
#define HW2   (HWPIX/2)          // 131072 (f2 granularity)
#define EPSV  1e-6f

#define WT_STRIDE 24             // padded row stride (floats): 96 B, 16B-aligned rows
#define WT_FLOATS (DD*WT_STRIDE) // 6144 floats = 24 KB
#define THREADS 256
#define MAIN_BLOCKS (HW2/THREADS) // 512
#define UND 8                    // d-loop unroll / prefetch depth

typedef float __attribute__((ext_vector_type(2))) f2;
typedef float __attribute__((ext_vector_type(4))) f4;
typedef int   __attribute__((ext_vector_type(2))) i2;

// ---------------- kernel 0: per-class norm + transposed weight table ----------------
// 21 blocks, one class each; block 0 also zeroes the completion counter.
__global__ void prep_weights(const float* __restrict__ w,  // [NCLS][DD]
                             float* __restrict__ wt,       // [DD][WT_STRIDE]
                             unsigned* __restrict__ counter)
{
    __shared__ float warr[4];
    __shared__ float inv_s;
    const int c = blockIdx.x, d = threadIdx.x;   // d in [0,256)
    if (c == 0 && d == 0) *counter = 0u;

    float v = w[c*DD + d];
    float s = v * v;
    #pragma unroll
    for (int off = 32; off; off >>= 1) s += __shfl_xor(s, off, 64);
    int wave = d >> 6, lane = d & 63;
    if (lane == 0) warr[wave] = s;
    __syncthreads();
    if (d == 0) inv_s = 1.0f / fmaxf(sqrtf(warr[0]+warr[1]+warr[2]+warr[3]), EPSV);
    __syncthreads();
    wt[d*WT_STRIDE + c] = v * inv_s;
}

// ---------------- kernel 1: fused per-pixel pass + block + final reduction ----------------
__global__ __launch_bounds__(THREADS, 2)
void main_kernel(const float* __restrict__ yp,    // [NCLS][HWPIX]
                 const int*   __restrict__ ycrf,  // [HWPIX]
                 const int*   __restrict__ yret,  // [HWPIX]
                 const float* __restrict__ fm,    // [DD][HWPIX]
                 const float* __restrict__ wt,    // [DD][WT_STRIDE] (normalized, transposed)
                 float* __restrict__ partials,    // [MAIN_BLOCKS][4]
                 unsigned* __restrict__ counter,
                 float* __restrict__ out)
{
    __shared__ float red[4][4];
    __shared__ bool amlast;

    const int tid = threadIdx.x;
    const int g = blockIdx.x * THREADS + tid;    // f2-pixel index
    const f2* fm2 = (const f2*)fm;
    const f2* yp2 = (const f2*)yp;
    const i2* yc2 = (const i2*)ycrf;
    const i2* yr2 = (const i2*)yret;

    float dot0[NCLS], dot1[NCLS];
    float nn0 = 0.f, nn1 = 0.f;
    #pragma unroll
    for (int c = 0; c < NCLS; ++c) { dot0[c] = 0.f; dot1[c] = 0.f; }

    // ---- dot products with normalized weights + feature norm ----
    f2 v[UND];
    #pragma unroll
    for (int u = 0; u < UND; ++u)
        v[u] = fm2[u*HW2 + g];

    for (int d0 = 0; d0 < DD; d0 += UND) {
        f2 nv[UND];
        if (d0 + UND < DD) {
            #pragma unroll
            for (int u = 0; u < UND; ++u)
                nv[u] = fm2[(d0 + UND + u)*HW2 + g];
        }
        #pragma unroll
        for (int u = 0; u < UND; ++u) {
            // wave-uniform weight row read (96 B): L1/K$ broadcast
            const f4* wr = (const f4*)(wt + (d0 + u)*WT_STRIDE);
            float wreg[24];
            #pragma unroll
            for (int i = 0; i < 6; ++i) ((f4*)wreg)[i] = wr[i];
            float vx = v[u].x, vy = v[u].y;
            #pragma unroll
            for (int c = 0; c < NCLS; ++c) {
                dot0[c] = fmaf(vx, wreg[c], dot0[c]);
                dot1[c] = fmaf(vy, wreg[c], dot1[c]);
            }
            nn0 = fmaf(vx, vx, nn0);
            nn1 = fmaf(vy, vy, nn1);
        }
        #pragma unroll
        for (int u = 0; u < UND; ++u) v[u] = nv[u];
    }

    const i2 yc = yc2[g], yr = yr2[g];

    // ---- corr / conf ----
    float inv_fn0 = 1.0f / fmaxf(sqrtf(nn0), EPSV);
    float inv_fn1 = 1.0f / fmaxf(sqrtf(nn1), EPSV);
    float cs0 = 0.f, cs1 = 0.f, cm0 = 0.f, cm1 = 0.f;  // cm init 0 == max(...,0)
    #pragma unroll
    for (int c = 0; c < NCLS; ++c) {
        float c0 = fmaf(dot0[c], inv_fn0, 1.0f);
        float c1 = fmaf(dot1[c], inv_fn1, 1.0f);
        cm0 = fmaxf(cm0, c0);
        cm1 = fmaxf(cm1, c1);
        cs0 = (yc.x == c) ? c0 : cs0;
        cs1 = (yc.y == c) ? c1 : cs1;
    }
    float r0 = cs0 / cm0, r1 = cs1 / cm1;
    float conf0 = r0 * r0, conf1 = r1 * r1;            // GAMMA = 2

    // ---- log-prob pass (21 independent loads, issued together) ----
    f2 p[NCLS];
    #pragma unroll
    for (int c = 0; c < NCLS; ++c)
        p[c] = yp2[c*HW2 + g];

    float slp0 = 0.f, slp1 = 0.f, lpc0 = 0.f, lpc1 = 0.f;
    #pragma unroll
    for (int c = 0; c < NCLS; ++c) {
        float l0 = __logf(p[c].x), l1 = __logf(p[c].y);
        slp0 += l0; slp1 += l1;
        lpc0 = (yc.x == c) ? l0 : lpc0;
        lpc1 = (yc.y == c) ? l1 : lpc1;
    }

    const bool s0 = (yc.x == yr.x), s1 = (yc.y == yr.y);
    float sl0 = s0 ? lpc0 : 0.f,  sl1 = s1 ? lpc1 : 0.f;
    float a_nce = sl0 + sl1;
    float a_dce = (s0 ? 1.f : 0.f) + (s1 ? 1.f : 0.f);
    float a_dw  = conf0 * ((float)NCLS - (s0 ? 1.f : 0.f))
                + conf1 * ((float)NCLS - (s1 ? 1.f : 0.f));
    float a_nw  = conf0 * (slp0 - sl0) + conf1 * (slp1 - sl1);

    // ---- block reduction ----
    #pragma unroll
    for (int off = 32; off; off >>= 1) {
        a_nce += __shfl_xor(a_nce, off, 64);
        a_dce += __shfl_xor(a_dce, off, 64);
        a_dw  += __shfl_xor(a_dw,  off, 64);
        a_nw  += __shfl_xor(a_nw,  off, 64);
    }
    int wave = tid >> 6, lane = tid & 63;
    if (lane == 0) { red[wave][0]=a_nce; red[wave][1]=a_dce; red[wave][2]=a_dw; red[wave][3]=a_nw; }
    __syncthreads();
    if (tid == 0) {
        #pragma unroll
        for (int i = 0; i < 4; ++i)
            partials[blockIdx.x*4 + i] = red[0][i] + red[1][i] + red[2][i] + red[3][i];
        __threadfence();                         // release partials
        unsigned old = atomicAdd(counter, 1u);
        amlast = (old == (unsigned)(MAIN_BLOCKS - 1));
    }
    __syncthreads();

    // ---- last block standing folds the final reduction ----
    if (amlast) {
        __threadfence();                         // acquire other blocks' partials
        float t0=0.f, t1=0.f, t2=0.f, t3=0.f;
        for (int b = tid; b < MAIN_BLOCKS; b += THREADS) {
            t0 += partials[b*4 + 0];
            t1 += partials[b*4 + 1];
            t2 += partials[b*4 + 2];
            t3 += partials[b*4 + 3];
        }
        #pragma unroll
        for (int off = 32; off; off >>= 1) {
            t0 += __shfl_xor(t0, off, 64);
            t1 += __shfl_xor(t1, off, 64);
            t2 += __shfl_xor(t2, off, 64);
            t3 += __shfl_xor(t3, off, 64);
        }
        __syncthreads();                         // red[] reuse
        if (lane == 0) { red[wave][0]=t0; red[wave][1]=t1; red[wave][2]=t2; red[wave][3]=t3; }
        __syncthreads();
        if (tid == 0) {
            float nce = red[0][0]+red[1][0]+red[2][0]+red[3][0];
            float dce = red[0][1]+red[1][1]+red[2][1]+red[3][1];
            float dw  = red[0][2]+red[1][2]+red[2][2]+red[3][2];
            float nw  = red[0][3]+red[1][3]+red[2][3]+red[3][3];
            float ce  = -nce / dce;
            float wce = -nw  / dw;
            out[0] = ce + 0.1f * wce;
            out[1] = ce;
            out[2] = wce;
        }
    }
}

extern "C" void kernel_launch(void* const* d_in, const int* in_sizes, int n_in,
                              void* d_out, int out_size, void* d_ws, size_t ws_size,
                              hipStream_t stream) {
    const float* y_pred = (const float*)d_in[0];
    const int*   ycrf   = (const int*)d_in[1];
    const int*   yret   = (const int*)d_in[2];
    const float* fmap   = (const float*)d_in[3];
    const float* cw     = (const float*)d_in[4];
    float* out = (float*)d_out;

    float*    wt       = (float*)d_ws;                 // 24 KB
    float*    partials = wt + WT_FLOATS;               // 512*4 floats = 8 KB
    unsigned* counter  = (unsigned*)(partials + MAIN_BLOCKS*4);

    prep_weights<<<NCLS, THREADS, 0, stream>>>(cw, wt, counter);
    main_kernel<<<MAIN_BLOCKS, THREADS, 0, stream>>>(y_pred, ycrf, yret, fmap, wt,
                                                     partials, counter, out);
}

// Round 6
// 90.884 us; speedup vs baseline: 1.0346x; 1.0346x over previous
//
#include <hip/hip_runtime.h>
#include <math.h>

#define NCLS 21
#define DD   256
#define HWPIX (512*512)          // 262144 pixels
#define HW2   (HWPIX/2)          // 131072 (f2 granularity)
#define EPSV  1e-6f

#define WT_STRIDE 24             // padded row stride (floats): 96 B, 16B-aligned rows
#define WT_FLOATS (DD*WT_STRIDE) // 6144 floats = 24 KB
#define THREADS 256
#define MAIN_BLOCKS (HW2/THREADS) // 512
#define UND 8                    // d-loop unroll / prefetch depth

typedef float __attribute__((ext_vector_type(2))) f2;
typedef float __attribute__((ext_vector_type(4))) f4;
typedef int   __attribute__((ext_vector_type(2))) i2;

// ---------------- kernel 0: per-class norm + transposed weight table ----------------
// 21 blocks, one class each; block 0 also zeroes the completion counter.
__global__ void prep_weights(const float* __restrict__ w,  // [NCLS][DD]
                             float* __restrict__ wt,       // [DD][WT_STRIDE]
                             unsigned* __restrict__ counter)
{
    __shared__ float warr[4];
    __shared__ float inv_s;
    const int c = blockIdx.x, d = threadIdx.x;   // d in [0,256)
    if (c == 0 && d == 0) *counter = 0u;

    float v = w[c*DD + d];
    float s = v * v;
    #pragma unroll
    for (int off = 32; off; off >>= 1) s += __shfl_xor(s, off, 64);
    int wave = d >> 6, lane = d & 63;
    if (lane == 0) warr[wave] = s;
    __syncthreads();
    if (d == 0) inv_s = 1.0f / fmaxf(sqrtf(warr[0]+warr[1]+warr[2]+warr[3]), EPSV);
    __syncthreads();
    wt[d*WT_STRIDE + c] = v * inv_s;
}

// ---------------- kernel 1: fused per-pixel pass + block + final reduction ----------------
__global__ __launch_bounds__(THREADS, 2)
void main_kernel(const float* __restrict__ yp,    // [NCLS][HWPIX]
                 const int*   __restrict__ ycrf,  // [HWPIX]
                 const int*   __restrict__ yret,  // [HWPIX]
                 const float* __restrict__ fm,    // [DD][HWPIX]
                 const float* __restrict__ wt,    // [DD][WT_STRIDE] (normalized, transposed)
                 float* __restrict__ partials,    // [MAIN_BLOCKS][4]
                 unsigned* __restrict__ counter,
                 float* __restrict__ out)
{
    __shared__ float red[4][4];
    __shared__ bool amlast;

    const int tid = threadIdx.x;
    const int g = blockIdx.x * THREADS + tid;    // f2-pixel index
    const f2* fm2 = (const f2*)fm;
    const f2* yp2 = (const f2*)yp;
    const i2* yc2 = (const i2*)ycrf;
    const i2* yr2 = (const i2*)yret;

    float dot0[NCLS], dot1[NCLS];
    float nn0 = 0.f, nn1 = 0.f;
    #pragma unroll
    for (int c = 0; c < NCLS; ++c) { dot0[c] = 0.f; dot1[c] = 0.f; }

    // ---- dot products with normalized weights + feature norm ----
    // NT loads: zero-reuse stream must NOT allocate in L1/L2 — keeps the
    // wave-uniform wt table L1-resident (R5 post-mortem: removing nt cost +19us).
    f2 v[UND];
    #pragma unroll
    for (int u = 0; u < UND; ++u)
        v[u] = __builtin_nontemporal_load(&fm2[u*HW2 + g]);

    for (int d0 = 0; d0 < DD; d0 += UND) {
        f2 nv[UND];
        if (d0 + UND < DD) {
            #pragma unroll
            for (int u = 0; u < UND; ++u)
                nv[u] = __builtin_nontemporal_load(&fm2[(d0 + UND + u)*HW2 + g]);
        }
        #pragma unroll
        for (int u = 0; u < UND; ++u) {
            // wave-uniform weight row read (96 B): L1/K$ broadcast
            const f4* wr = (const f4*)(wt + (d0 + u)*WT_STRIDE);
            float wreg[24];
            #pragma unroll
            for (int i = 0; i < 6; ++i) ((f4*)wreg)[i] = wr[i];
            float vx = v[u].x, vy = v[u].y;
            #pragma unroll
            for (int c = 0; c < NCLS; ++c) {
                dot0[c] = fmaf(vx, wreg[c], dot0[c]);
                dot1[c] = fmaf(vy, wreg[c], dot1[c]);
            }
            nn0 = fmaf(vx, vx, nn0);
            nn1 = fmaf(vy, vy, nn1);
        }
        #pragma unroll
        for (int u = 0; u < UND; ++u) v[u] = nv[u];
    }

    const i2 yc = yc2[g], yr = yr2[g];

    // ---- corr / conf ----
    float inv_fn0 = 1.0f / fmaxf(sqrtf(nn0), EPSV);
    float inv_fn1 = 1.0f / fmaxf(sqrtf(nn1), EPSV);
    float cs0 = 0.f, cs1 = 0.f, cm0 = 0.f, cm1 = 0.f;  // cm init 0 == max(...,0)
    #pragma unroll
    for (int c = 0; c < NCLS; ++c) {
        float c0 = fmaf(dot0[c], inv_fn0, 1.0f);
        float c1 = fmaf(dot1[c], inv_fn1, 1.0f);
        cm0 = fmaxf(cm0, c0);
        cm1 = fmaxf(cm1, c1);
        cs0 = (yc.x == c) ? c0 : cs0;
        cs1 = (yc.y == c) ? c1 : cs1;
    }
    float r0 = cs0 / cm0, r1 = cs1 / cm1;
    float conf0 = r0 * r0, conf1 = r1 * r1;            // GAMMA = 2

    // ---- log-prob pass (21 independent NT loads, issued together) ----
    f2 p[NCLS];
    #pragma unroll
    for (int c = 0; c < NCLS; ++c)
        p[c] = __builtin_nontemporal_load(&yp2[c*HW2 + g]);

    float slp0 = 0.f, slp1 = 0.f, lpc0 = 0.f, lpc1 = 0.f;
    #pragma unroll
    for (int c = 0; c < NCLS; ++c) {
        float l0 = __logf(p[c].x), l1 = __logf(p[c].y);
        slp0 += l0; slp1 += l1;
        lpc0 = (yc.x == c) ? l0 : lpc0;
        lpc1 = (yc.y == c) ? l1 : lpc1;
    }

    const bool s0 = (yc.x == yr.x), s1 = (yc.y == yr.y);
    float sl0 = s0 ? lpc0 : 0.f,  sl1 = s1 ? lpc1 : 0.f;
    float a_nce = sl0 + sl1;
    float a_dce = (s0 ? 1.f : 0.f) + (s1 ? 1.f : 0.f);
    float a_dw  = conf0 * ((float)NCLS - (s0 ? 1.f : 0.f))
                + conf1 * ((float)NCLS - (s1 ? 1.f : 0.f));
    float a_nw  = conf0 * (slp0 - sl0) + conf1 * (slp1 - sl1);

    // ---- block reduction ----
    #pragma unroll
    for (int off = 32; off; off >>= 1) {
        a_nce += __shfl_xor(a_nce, off, 64);
        a_dce += __shfl_xor(a_dce, off, 64);
        a_dw  += __shfl_xor(a_dw,  off, 64);
        a_nw  += __shfl_xor(a_nw,  off, 64);
    }
    int wave = tid >> 6, lane = tid & 63;
    if (lane == 0) { red[wave][0]=a_nce; red[wave][1]=a_dce; red[wave][2]=a_dw; red[wave][3]=a_nw; }
    __syncthreads();
    if (tid == 0) {
        #pragma unroll
        for (int i = 0; i < 4; ++i)
            partials[blockIdx.x*4 + i] = red[0][i] + red[1][i] + red[2][i] + red[3][i];
        __threadfence();                         // release partials
        unsigned old = atomicAdd(counter, 1u);
        amlast = (old == (unsigned)(MAIN_BLOCKS - 1));
    }
    __syncthreads();

    // ---- last block standing folds the final reduction ----
    if (amlast) {
        __threadfence();                         // acquire other blocks' partials
        float t0=0.f, t1=0.f, t2=0.f, t3=0.f;
        for (int b = tid; b < MAIN_BLOCKS; b += THREADS) {
            t0 += partials[b*4 + 0];
            t1 += partials[b*4 + 1];
            t2 += partials[b*4 + 2];
            t3 += partials[b*4 + 3];
        }
        #pragma unroll
        for (int off = 32; off; off >>= 1) {
            t0 += __shfl_xor(t0, off, 64);
            t1 += __shfl_xor(t1, off, 64);
            t2 += __shfl_xor(t2, off, 64);
            t3 += __shfl_xor(t3, off, 64);
        }
        __syncthreads();                         // red[] reuse
        if (lane == 0) { red[wave][0]=t0; red[wave][1]=t1; red[wave][2]=t2; red[wave][3]=t3; }
        __syncthreads();
        if (tid == 0) {
            float nce = red[0][0]+red[1][0]+red[2][0]+red[3][0];
            float dce = red[0][1]+red[1][1]+red[2][1]+red[3][1];
            float dw  = red[0][2]+red[1][2]+red[2][2]+red[3][2];
            float nw  = red[0][3]+red[1][3]+red[2][3]+red[3][3];
            float ce  = -nce / dce;
            float wce = -nw  / dw;
            out[0] = ce + 0.1f * wce;
            out[1] = ce;
            out[2] = wce;
        }
    }
}

extern "C" void kernel_launch(void* const* d_in, const int* in_sizes, int n_in,
                              void* d_out, int out_size, void* d_ws, size_t ws_size,
                              hipStream_t stream) {
    const float* y_pred = (const float*)d_in[0];
    const int*   ycrf   = (const int*)d_in[1];
    const int*   yret   = (const int*)d_in[2];
    const float* fmap   = (const float*)d_in[3];
    const float* cw     = (const float*)d_in[4];
    float* out = (float*)d_out;

    float*    wt       = (float*)d_ws;                 // 24 KB
    float*    partials = wt + WT_FLOATS;               // 512*4 floats = 8 KB
    unsigned* counter  = (unsigned*)(partials + MAIN_BLOCKS*4);

    prep_weights<<<NCLS, THREADS, 0, stream>>>(cw, wt, counter);
    main_kernel<<<MAIN_BLOCKS, THREADS, 0, stream>>>(y_pred, ycrf, yret, fmap, wt,
                                                     partials, counter, out);
}